// Round 2
// 746.684 us; speedup vs baseline: 1.0672x; 1.0672x over previous
//
#include <hip/hip_runtime.h>

// L2Similarity: out[n][m] = -||x_n - g_m||  for x:[8192,128] f32, g:[16384,128] f32
// = -sqrt(max(||x||^2 + ||g||^2 - 2 x.g, 0))
//
// R4 = R3 with the __sqrtf -> sqrtf compile fix.
// R3 design: barrier-free, LDS-free streaming.
// R2 was latency-bound (VALUBusy 31%, MfmaUtil 3.6%, Occ 24%, HBM 1.6 of 6.3 TB/s):
// 2 blocks/CU in lockstep between barriers; stage/MFMA/epilogue phases serialized.
// Output write (512 MB) sets an ~85us floor; everything else must hide under it.
//  (1) each wave owns an independent 64x64 output tile (4x4 of 16x16x32 bf16 MFMA);
//  (2) A/B fragments loaded DIRECTLY from global in MFMA layout (inputs are 12 MB,
//      L2/L3-resident; per-row 128B lines are consumed exactly once by the 4 quads);
//  (3) f32->bf16 via v_cvt_pk_bf16_f32 (1 instr per 2 elems vs 4 per elem manual RNE);
//  (4) row norms computed in-register from the same loads: per-lane partial sumsq,
//      quad-group shfl_xor(16,32) completes; epilogue xsq via shfl, gsq lane-local;
//  (5) NO __shared__, NO __syncthreads -> waves desync and the store stream overlaps
//      loads/compute across 12 waves/CU.
// Predicted: dur 390 -> ~110-160 us/dispatch, write BW -> 3.5-4.5 TB/s, Occ -> ~36%.

#define N_IMG 8192
#define N_GTS 16384
#define K_DIM 128

typedef __attribute__((ext_vector_type(8))) short short8;   // 8 bf16 = 4 VGPRs
typedef __attribute__((ext_vector_type(4))) float f32x4;

// two float4 (8 consecutive f32) -> 8 bf16 (RNE), via packed hw convert
__device__ __forceinline__ short8 cvt8(const float4& a, const float4& b) {
    union { short8 s; unsigned int u[4]; } r;
    asm("v_cvt_pk_bf16_f32 %0, %1, %2" : "=v"(r.u[0]) : "v"(a.x), "v"(a.y));
    asm("v_cvt_pk_bf16_f32 %0, %1, %2" : "=v"(r.u[1]) : "v"(a.z), "v"(a.w));
    asm("v_cvt_pk_bf16_f32 %0, %1, %2" : "=v"(r.u[2]) : "v"(b.x), "v"(b.y));
    asm("v_cvt_pk_bf16_f32 %0, %1, %2" : "=v"(r.u[3]) : "v"(b.z), "v"(b.w));
    return r.s;
}

__global__ __launch_bounds__(256, 3)
void l2sim_kernel(const float* __restrict__ A, const float* __restrict__ G,
                  float* __restrict__ out)
{
    const int t    = threadIdx.x;
    const int wave = t >> 6;
    const int lane = t & 63;
    const int lm   = lane & 15;   // MFMA row index within 16-tile (m for A, n for B)
    const int quad = lane >> 4;   // k-offset selector: k = ks*32 + quad*8

    // 2x2 waves over a 128x128 block tile; each wave: 64x64 outputs
    const int wtm = blockIdx.y * 128 + (wave & 1) * 64;   // image rows
    const int wtn = blockIdx.x * 128 + (wave >> 1) * 64;  // gts rows

    // per-lane row base pointers (already offset by quad*8 in k)
    const float* aRow[4];
    const float* gRow[4];
    #pragma unroll
    for (int i = 0; i < 4; ++i) {
        aRow[i] = A + (size_t)(wtm + i * 16 + lm) * K_DIM + quad * 8;
        gRow[i] = G + (size_t)(wtn + i * 16 + lm) * K_DIM + quad * 8;
    }

    f32x4 acc[4][4] = {};                  // [mi][ni], C layout: col=lm, row=quad*4+r
    float xsq[4] = {0.f, 0.f, 0.f, 0.f};   // partial sumsq of A row (wtm+mi*16+lm)
    float gsq[4] = {0.f, 0.f, 0.f, 0.f};   // partial sumsq of G row (wtn+ni*16+lm)

    #pragma unroll
    for (int ks = 0; ks < 4; ++ks) {       // K = 4 steps of 32
        short8 af[4], bfr[4];
        #pragma unroll
        for (int mi = 0; mi < 4; ++mi) {
            float4 v0 = *(const float4*)(aRow[mi] + ks * 32);
            float4 v1 = *(const float4*)(aRow[mi] + ks * 32 + 4);
            xsq[mi] += v0.x*v0.x + v0.y*v0.y + v0.z*v0.z + v0.w*v0.w
                     + v1.x*v1.x + v1.y*v1.y + v1.z*v1.z + v1.w*v1.w;
            af[mi] = cvt8(v0, v1);
        }
        #pragma unroll
        for (int ni = 0; ni < 4; ++ni) {
            float4 v0 = *(const float4*)(gRow[ni] + ks * 32);
            float4 v1 = *(const float4*)(gRow[ni] + ks * 32 + 4);
            gsq[ni] += v0.x*v0.x + v0.y*v0.y + v0.z*v0.z + v0.w*v0.w
                     + v1.x*v1.x + v1.y*v1.y + v1.z*v1.z + v1.w*v1.w;
            bfr[ni] = cvt8(v0, v1);
        }
        #pragma unroll
        for (int mi = 0; mi < 4; ++mi)
            #pragma unroll
            for (int ni = 0; ni < 4; ++ni)
                acc[mi][ni] = __builtin_amdgcn_mfma_f32_16x16x32_bf16(
                    af[mi], bfr[ni], acc[mi][ni], 0, 0, 0);
    }

    // complete row norms: each lane covered k = {ks*32 + quad*8 .. +7};
    // the 4 quad lanes of an lm-group together cover all 128 k exactly once.
    #pragma unroll
    for (int i = 0; i < 4; ++i) {
        xsq[i] += __shfl_xor(xsq[i], 16);
        xsq[i] += __shfl_xor(xsq[i], 32);
        gsq[i] += __shfl_xor(gsq[i], 16);
        gsq[i] += __shfl_xor(gsq[i], 32);
    }
    // now every lane holds the FULL norm for its lm-indexed rows.

    // epilogue: d2 = xsq + gsq - 2*dot; out = -sqrt(max(d2,0))
    float* outBase = out + (size_t)wtm * N_GTS + wtn;
    #pragma unroll
    for (int mi = 0; mi < 4; ++mi) {
        #pragma unroll
        for (int r = 0; r < 4; ++r) {
            // acc row index within 16-tile is quad*4+r; fetch that row's norm
            // from the lane that owns it (lane id = quad*4+r, 0..15)
            float xs = __shfl(xsq[mi], quad * 4 + r);
            float* orow = outBase + (size_t)(mi * 16 + quad * 4 + r) * N_GTS;
            #pragma unroll
            for (int ni = 0; ni < 4; ++ni) {
                float d2 = fmaxf(xs + gsq[ni] - 2.0f * acc[mi][ni][r], 0.0f);
                orow[ni * 16 + lm] = -sqrtf(d2);
            }
        }
    }
}

extern "C" void kernel_launch(void* const* d_in, const int* in_sizes, int n_in,
                              void* d_out, int out_size, void* d_ws, size_t ws_size,
                              hipStream_t stream) {
    const float* A = (const float*)d_in[0];   // image_features [8192,128]
    const float* G = (const float*)d_in[1];   // gts            [16384,128]
    float* out = (float*)d_out;               // [8192,16384]
    dim3 grid(N_GTS / 128, N_IMG / 128);      // (128, 64)
    l2sim_kernel<<<grid, 256, 0, stream>>>(A, G, out);
}